// Round 10
// baseline (784.437 us; speedup 1.0000x reference)
//
#include <hip/hip_runtime.h>
#include <hip/hip_bf16.h>

#define N_TOK   8192
#define DM      1024     // d_model
#define DH      16384    // d_hidden
#define KTOP    32
#define NCAND   512      // candidate capacity per row (atomic-range packed)
#define CSLOT   16       // LDS slots per (row, 128-col slice); Poisson(~1.8)
#define CAND_T  2.2f     // fixed threshold (validated end-to-end rounds 3/6/7/9)
#define DZ      0.08f    // zone half-width >= gemm err (0.031) + bf16 quant (0.008)

typedef unsigned int uint;
typedef __attribute__((ext_vector_type(8))) short bf16x8;
typedef __attribute__((ext_vector_type(4))) float f32x4;
typedef __attribute__((ext_vector_type(2))) float f32x2;

__device__ inline ushort f2bf(float f) {
    uint u = __float_as_uint(f);
    uint r = (u + 0x7FFFu + ((u >> 16) & 1u)) >> 16;
    return (ushort)r;
}
__device__ inline float bf2f(ushort u) {
    return __uint_as_float(((uint)u) << 16);
}

__device__ inline void load_lds16(const void* g, void* l) {
    __builtin_amdgcn_global_load_lds(
        (const __attribute__((address_space(1))) void*)g,
        (__attribute__((address_space(3))) void*)l, 16, 0, 0);
}

// ---------------------------------------------------------------------------
// Fused conversion: A = bf16(x - b_pre) [N_TOK,DM]; B = bf16(W_enc) [DH,DM]
// ---------------------------------------------------------------------------
#define NA (N_TOK * DM)
__global__ __launch_bounds__(256) void conv_fused(
    const float* __restrict__ x, const float* __restrict__ b_pre,
    const float* __restrict__ W, ushort* __restrict__ A, ushort* __restrict__ B)
{
    int i = (blockIdx.x * 256 + threadIdx.x) * 4;
    if (i < NA) {
        float4 v = *(const float4*)&x[i];
        float4 b = *(const float4*)&b_pre[i & (DM - 1)];
        ushort4 o;
        o.x = f2bf(v.x - b.x); o.y = f2bf(v.y - b.y);
        o.z = f2bf(v.z - b.z); o.w = f2bf(v.w - b.w);
        *(ushort4*)&A[i] = o;
    } else {
        int j = i - NA;
        float4 v = *(const float4*)&W[j];
        ushort4 o;
        o.x = f2bf(v.x); o.y = f2bf(v.y); o.z = f2bf(v.z); o.w = f2bf(v.w);
        *(ushort4*)&B[j] = o;
    }
}

// ---------------------------------------------------------------------------
// bf16 MFMA GEMM (m97 128x128 structure, 3 blocks/CU), SWAPPED-OPERAND
// accumulator (D rows = h, D cols = token) so the 4 acc regs per fragment
// are 4 consecutive h -> coalesced f32x4 nt-stores (16 stores/thread vs 64).
// Fused candidate extraction (LDS-aggregated, exact-count atomic packing).
// ---------------------------------------------------------------------------
__global__ __launch_bounds__(256, 3) void gemm_bf16(
    const ushort* __restrict__ A, const ushort* __restrict__ B,
    const float* __restrict__ b_act, float* __restrict__ pre,
    uint* __restrict__ cand, int* __restrict__ ccnt, uint* __restrict__ flags)
{
    __shared__ ushort As[128 * 64];   // 16 KB
    __shared__ ushort Bs[128 * 64];   // 16 KB

    const int tid  = threadIdx.x;
    const int wid  = tid >> 6;
    const int lane = tid & 63;
    const int wr   = wid >> 1;        // wave row (token) 0..1
    const int wc   = wid & 1;         // wave col (h) 0..1

    // XCD-aware bijective swizzle (8192 % 8 == 0), bn-major for L2 B reuse
    int swz = (blockIdx.x & 7) * 1024 + (blockIdx.x >> 3);
    const int bm = swz & 63;          // 64 row tiles (tokens)
    const int bn = swz >> 6;          // 128 col tiles (h)
    const int row0 = bm * 128;
    const int col0 = bn * 128;

    f32x4 acc[4][4] = {};             // [hf][tf] (swapped: rows = h)

    const int chunk = wid * 64 + lane;
    for (int k0 = 0; k0 < DM; k0 += 64) {
        #pragma unroll
        for (int i = 0; i < 4; ++i) {
            int ch = i * 256 + chunk;
            int r  = ch >> 3;
            int c8 = (ch & 7) * 8;
            load_lds16(&A[(size_t)(row0 + r) * DM + k0 + c8],
                       &As[(size_t)(i * 256 + wid * 64) * 8]);
            load_lds16(&B[(size_t)(col0 + r) * DM + k0 + c8],
                       &Bs[(size_t)(i * 256 + wid * 64) * 8]);
        }
        __syncthreads();
        #pragma unroll
        for (int ks = 0; ks < 2; ++ks) {
            const int kb = ks * 32 + (lane >> 4) * 8;
            bf16x8 af[4], bfr[4];
            #pragma unroll
            for (int m = 0; m < 4; ++m)
                af[m] = *(const bf16x8*)&As[(wr * 64 + m * 16 + (lane & 15)) * 64 + kb];
            #pragma unroll
            for (int n = 0; n < 4; ++n)
                bfr[n] = *(const bf16x8*)&Bs[(wc * 64 + n * 16 + (lane & 15)) * 64 + kb];
            // swapped operands: D = B_frag . A_frag  ->  D[h][token]
            #pragma unroll
            for (int hf = 0; hf < 4; ++hf)
                #pragma unroll
                for (int tf = 0; tf < 4; ++tf)
                    acc[hf][tf] = __builtin_amdgcn_mfma_f32_16x16x32_bf16(
                        bfr[hf], af[tf], acc[hf][tf], 0, 0, 0);
        }
        __syncthreads();
    }

    // ---- epilogue: coalesced f32x4 C-write (nt) + LDS candidate aggregation
    uint* cnt = (uint*)As;             // [128]
    uint* buf = (uint*)As + 128;       // [128][CSLOT]  (8.7 KB, aliases As)
    if (tid < 128) cnt[tid] = 0;
    __syncthreads();

    // per-hf bias: 4 consecutive b_act at h0 (register-contiguous dim)
    f32x4 ba[4];
    #pragma unroll
    for (int hf = 0; hf < 4; ++hf)
        ba[hf] = *(const f32x4*)&b_act[col0 + wc * 64 + hf * 16 + (lane >> 4) * 4];

    #pragma unroll
    for (int hf = 0; hf < 4; ++hf) {
        const int h0 = col0 + wc * 64 + hf * 16 + (lane >> 4) * 4;
        #pragma unroll
        for (int tf = 0; tf < 4; ++tf) {
            const int ltok = wr * 64 + tf * 16 + (lane & 15);   // local token
            f32x4 o = acc[hf][tf] + ba[hf];
            __builtin_nontemporal_store(
                o, (f32x4*)&pre[(size_t)(row0 + ltok) * DH + h0]);
            #pragma unroll
            for (int c = 0; c < 4; ++c) {
                if (o[c] > CAND_T) {
                    uint pos = atomicAdd(&cnt[ltok], 1u);
                    if (pos < CSLOT)
                        buf[ltok * CSLOT + pos] =
                            ((uint)f2bf(o[c]) << 16) | (uint)(16383 - (h0 + c));
                }
            }
        }
    }
    __syncthreads();
    if (tid < 128) {
        uint c = cnt[tid];
        if (c > 0) {
            uint m = c < CSLOT ? c : CSLOT;
            uint base = (uint)atomicAdd(&ccnt[row0 + tid], (int)m);
            if (c > CSLOT || base + c > NCAND) flags[row0 + tid] = 1u;
            for (uint k = 0; k < m && base + k < NCAND; ++k)
                cand[(size_t)(row0 + tid) * NCAND + base + k] = buf[tid * CSLOT + k];
        }
    }
}

// ---------------------------------------------------------------------------
// Fused top-32 + decode (unchanged from measured round-9 kernel).
// ---------------------------------------------------------------------------
__global__ __launch_bounds__(512) void topk_recon(
    const float* __restrict__ x, const float* __restrict__ b_pre,
    const float* __restrict__ W, const float* __restrict__ b_act,
    const uint* __restrict__ cand, const int* __restrict__ ccnt,
    const uint* __restrict__ flags, const float* __restrict__ pre,
    const ushort* __restrict__ wdecT,
    float* __restrict__ sparse, float* __restrict__ recon)
{
    const int row = blockIdx.x;
    const int tid = threadIdx.x;
    const int wid = tid >> 6, lane = tid & 63;

    // zero sparse row (4096 x 16B / 512 threads, nontemporal)
    f32x4 z4 = {0.f, 0.f, 0.f, 0.f};
    f32x4* srow = (f32x4*)(sparse + (size_t)row * DH);
    #pragma unroll
    for (int i = 0; i < 8; ++i)
        __builtin_nontemporal_store(z4, &srow[tid + i * 512]);

    __shared__ float xs[DM];
    for (int i = tid; i < DM; i += 512)
        xs[i] = x[(size_t)row * DM + i] - b_pre[i];

    __shared__ float sv[NCAND];
    __shared__ float sex[NCAND];
    __shared__ int   si[NCAND];
    __shared__ int   zlist[NCAND];
    __shared__ float svals[KTOP];
    __shared__ int   sinds[KTOP];
    __shared__ float sa32;
    __shared__ int   scin, zn, nl;

    int n = min(ccnt[row], NCAND);
    {
        uint pk = (tid < n) ? cand[(size_t)row * NCAND + tid] : 0u;
        sv[tid] = (tid < n) ? bf2f((ushort)(pk >> 16)) : -1e30f;
        si[tid] = (tid < n) ? (int)(16383u - (pk & 0x3FFFu)) : -1;
    }
    if (tid == 0) { scin = 0; zn = 0; sa32 = -1e30f; }
    if (tid < KTOP) { svals[tid] = 0.f; sinds[tid] = -1; }
    __syncthreads();

    // fallback (expected ~never): overflow or degenerate
    const bool fb = (flags[row] != 0u) || n < 64;
    if (fb) {
        sv[tid] = -1e30f; si[tid] = -1;
        if (tid == 0) nl = 0;
        __syncthreads();
        const float* __restrict__ p = pre + (size_t)row * DH;
        float v[32];
        #pragma unroll
        for (int j = 0; j < 32; ++j) v[j] = p[j * 512 + tid];

        __shared__ int scount;
        float lo = -30.f, hi = 30.f, t = 0.f;
        for (int it = 0; it < 20; ++it) {
            t = 0.5f * (lo + hi);
            int c = 0;
            #pragma unroll
            for (int j = 0; j < 32; ++j) c += (v[j] > t);
            #pragma unroll
            for (int off = 32; off; off >>= 1) c += __shfl_down(c, off);
            if (tid == 0) scount = 0;
            __syncthreads();
            if ((tid & 63) == 0) atomicAdd(&scount, c);
            __syncthreads();
            int total = scount;
            __syncthreads();
            if (total >= 96 && total <= 450) break;
            if (total < 96) hi = t; else lo = t;
        }
        #pragma unroll
        for (int j = 0; j < 32; ++j) {
            if (v[j] > t) {
                int p2 = atomicAdd(&nl, 1);
                if (p2 < NCAND) { sv[p2] = v[j]; si[p2] = j * 512 + tid; }
            }
        }
        __syncthreads();
        n = min(nl, NCAND);
    }

    const float v  = sv[tid];
    const int   id = si[tid];
    sex[tid] = v;
    __syncthreads();

    // rank by count (val desc, idx asc), bounded to n (padded to 64)
    const int n_pad = (n + 63) & ~63;
    int rank = 0;
    for (int j = 0; j < n_pad; ++j) {
        float ov = sv[j];
        rank += (ov > v) || (ov == v && si[j] < id);
    }
    if (rank == 31) sa32 = v;
    __syncthreads();

    const float a32 = sa32;
    const bool cin  = v > a32 + DZ;
    const bool zone = !cin && (v >= a32 - DZ) && (id >= 0);

    unsigned long long bal = __ballot(cin);
    if (lane == 0) atomicAdd(&scin, (int)__popcll(bal));
    if (zone) { int p = atomicAdd(&zn, 1); zlist[p] = tid; }
    __syncthreads();

    const int cin_total = scin;
    const int znum = zn;

    // exact f32 recompute of zone members, one per wave (W rows L3-resident)
    for (int m = wid; m < znum; m += 8) {
        int t = zlist[m];
        int h = si[t];
        const float* wrow = W + (size_t)h * DM;
        float s = 0.f;
        #pragma unroll
        for (int c = 0; c < 16; ++c)
            s = fmaf(xs[lane + c * 64], wrow[lane + c * 64], s);
        #pragma unroll
        for (int off = 32; off; off >>= 1) s += __shfl_down(s, off);
        if (lane == 0) sex[t] = s + b_act[h];
    }
    __syncthreads();

    int slot = -1;
    float outv = 0.f;
    if (cin) { slot = rank; outv = v; }
    else if (zone) {
        float ev = sex[tid];
        int zrank = 0;
        for (int j = 0; j < znum; ++j) {
            int t2 = zlist[j];
            float ov = sex[t2];
            zrank += (ov > ev) || (ov == ev && si[t2] < id);
        }
        if (zrank < KTOP - cin_total) { slot = cin_total + zrank; outv = ev; }
    }
    if (slot >= 0 && slot < KTOP) {
        float r = fmaxf(outv, 0.f);
        svals[slot] = r;
        sinds[slot] = id;
        sparse[(size_t)row * DH + id] = r;
    }
    __syncthreads();

    // ---- fused decode: recon[row][d] = sum_j svals[j]*wdecT[sinds[j]][d]+b_pre[d]
    const int d0 = tid * 2;
    f32x2 a;
    a.x = b_pre[d0]; a.y = b_pre[d0 + 1];
    #pragma unroll 8
    for (int j = 0; j < KTOP; ++j) {
        float vj = svals[j];
        int h = sinds[j];
        if (vj != 0.f && h >= 0) {
            ushort2 w = *(const ushort2*)&wdecT[(size_t)h * DM + d0];
            a.x = fmaf(vj, bf2f(w.x), a.x);
            a.y = fmaf(vj, bf2f(w.y), a.y);
        }
    }
    __builtin_nontemporal_store(a, (f32x2*)&recon[(size_t)row * DM + d0]);
}

// ---------------------------------------------------------------------------
// Transpose W_dec [DM, DH] f32 -> W_dec^T [DH, DM] bf16
// ---------------------------------------------------------------------------
__global__ __launch_bounds__(256) void transpose_dec(
    const float* __restrict__ W, ushort* __restrict__ WT)
{
    __shared__ float t[32][33];
    const int tx = threadIdx.x;
    const int ty = threadIdx.y;
    const int h0 = blockIdx.x * 32;
    const int d0 = blockIdx.y * 32;
    #pragma unroll
    for (int r = 0; r < 4; ++r)
        t[ty + r * 8][tx] = W[(size_t)(d0 + ty + r * 8) * DH + h0 + tx];
    __syncthreads();
    #pragma unroll
    for (int r = 0; r < 4; ++r)
        WT[(size_t)(h0 + ty + r * 8) * DM + d0 + tx] = f2bf(t[tx][ty + r * 8]);
}

// ---------------------------------------------------------------------------
extern "C" void kernel_launch(void* const* d_in, const int* in_sizes, int n_in,
                              void* d_out, int out_size, void* d_ws, size_t ws_size,
                              hipStream_t stream)
{
    const float* x     = (const float*)d_in[0];
    const float* W_enc = (const float*)d_in[1];
    const float* W_dec = (const float*)d_in[2];
    const float* b_pre = (const float*)d_in[3];
    const float* b_act = (const float*)d_in[4];

    float* recon  = (float*)d_out;                       // [N, DM]
    float* sparse = recon + (size_t)N_TOK * DM;          // [N, DH]
    float* pre    = sparse + (size_t)N_TOK * DH;         // [N, DH]

    // bf16 staging of A/B inside the sparse output region (zeroed later by
    // topk_recon, which runs after gemm has consumed them)
    ushort* Abf = (ushort*)sparse;                       // 16.8 MB
    ushort* Bbf = Abf + (size_t)N_TOK * DM;              // 33.5 MB

    // workspace (~50.4 MB, under proven 52.4 MB footprint)
    int*    ccnt  = (int*)d_ws;                                   // 32 KB
    uint*   flags = (uint*)(ccnt + N_TOK);                        // 32 KB
    uint*   cand  = (uint*)(flags + N_TOK);                       // 16.78 MB
    ushort* wdecT = (ushort*)(cand + (size_t)N_TOK * NCAND);      // 33.5 MB

    // zero counters + flags only (64 KB; stale cand beyond count never read)
    (void)hipMemsetAsync(ccnt, 0, 2 * N_TOK * sizeof(int), stream);

    conv_fused<<<(NA + DH * DM) / 1024, 256, 0, stream>>>(x, b_pre, W_enc, Abf, Bbf);

    gemm_bf16<<<(N_TOK / 128) * (DH / 128), 256, 0, stream>>>(
        Abf, Bbf, b_act, pre, cand, ccnt, flags);

    transpose_dec<<<dim3(DH / 32, DM / 32), dim3(32, 8), 0, stream>>>(W_dec, wdecT);

    topk_recon<<<N_TOK, 512, 0, stream>>>(x, b_pre, W_enc, b_act,
                                          cand, ccnt, flags, pre, wdecT,
                                          sparse, recon);
}

// Round 11
// 766.012 us; speedup vs baseline: 1.0241x; 1.0241x over previous
//
#include <hip/hip_runtime.h>
#include <hip/hip_bf16.h>

#define N_TOK   8192
#define DM      1024     // d_model
#define DH      16384    // d_hidden
#define KTOP    32
#define NCAND   512      // candidate capacity per row (atomic-range packed)
#define CSLOT   16       // LDS slots per (row, 128-col slice); Poisson(~1.8)
#define CAND_T  2.2f     // fixed threshold (validated end-to-end rounds 3/6/7/9/10)
#define DZ      0.06f    // zone half-width >= gemm err (0.031) + bf16 quant (0.008)

typedef unsigned int uint;
typedef __attribute__((ext_vector_type(8))) short bf16x8;
typedef __attribute__((ext_vector_type(4))) float f32x4;
typedef __attribute__((ext_vector_type(2))) float f32x2;

__device__ inline ushort f2bf(float f) {
    uint u = __float_as_uint(f);
    uint r = (u + 0x7FFFu + ((u >> 16) & 1u)) >> 16;
    return (ushort)r;
}
__device__ inline float bf2f(ushort u) {
    return __uint_as_float(((uint)u) << 16);
}

__device__ inline void load_lds16(const void* g, void* l) {
    __builtin_amdgcn_global_load_lds(
        (const __attribute__((address_space(1))) void*)g,
        (__attribute__((address_space(3))) void*)l, 16, 0, 0);
}

// ---------------------------------------------------------------------------
// Fused conversion: A = bf16(x - b_pre) [N_TOK,DM]; B = bf16(W_enc) [DH,DM]
// ---------------------------------------------------------------------------
#define NA (N_TOK * DM)
__global__ __launch_bounds__(256) void conv_fused(
    const float* __restrict__ x, const float* __restrict__ b_pre,
    const float* __restrict__ W, ushort* __restrict__ A, ushort* __restrict__ B)
{
    int i = (blockIdx.x * 256 + threadIdx.x) * 4;
    if (i < NA) {
        float4 v = *(const float4*)&x[i];
        float4 b = *(const float4*)&b_pre[i & (DM - 1)];
        ushort4 o;
        o.x = f2bf(v.x - b.x); o.y = f2bf(v.y - b.y);
        o.z = f2bf(v.z - b.z); o.w = f2bf(v.w - b.w);
        *(ushort4*)&A[i] = o;
    } else {
        int j = i - NA;
        float4 v = *(const float4*)&W[j];
        ushort4 o;
        o.x = f2bf(v.x); o.y = f2bf(v.y); o.z = f2bf(v.z); o.w = f2bf(v.w);
        *(ushort4*)&B[j] = o;
    }
}

// ---------------------------------------------------------------------------
// bf16 MFMA GEMM (m97 128x128 structure), swapped-operand accumulator
// (D rows = h -> f32x4 coalesced nt-stores), fused candidate extraction.
// __launch_bounds__(256, 4): 4 blocks/CU (16 waves) for deeper cross-block
// TLP to hide barrier/staging drains (round-11 probe; was 3).
// ---------------------------------------------------------------------------
__global__ __launch_bounds__(256, 4) void gemm_bf16(
    const ushort* __restrict__ A, const ushort* __restrict__ B,
    const float* __restrict__ b_act, float* __restrict__ pre,
    uint* __restrict__ cand, int* __restrict__ ccnt, uint* __restrict__ flags)
{
    __shared__ ushort As[128 * 64];   // 16 KB
    __shared__ ushort Bs[128 * 64];   // 16 KB

    const int tid  = threadIdx.x;
    const int wid  = tid >> 6;
    const int lane = tid & 63;
    const int wr   = wid >> 1;        // wave row (token) 0..1
    const int wc   = wid & 1;         // wave col (h) 0..1

    // XCD-aware bijective swizzle (8192 % 8 == 0), bn-major for L2 B reuse
    int swz = (blockIdx.x & 7) * 1024 + (blockIdx.x >> 3);
    const int bm = swz & 63;          // 64 row tiles (tokens)
    const int bn = swz >> 6;          // 128 col tiles (h)
    const int row0 = bm * 128;
    const int col0 = bn * 128;

    f32x4 acc[4][4] = {};             // [hf][tf] (swapped: rows = h)

    const int chunk = wid * 64 + lane;
    for (int k0 = 0; k0 < DM; k0 += 64) {
        #pragma unroll
        for (int i = 0; i < 4; ++i) {
            int ch = i * 256 + chunk;
            int r  = ch >> 3;
            int c8 = (ch & 7) * 8;
            load_lds16(&A[(size_t)(row0 + r) * DM + k0 + c8],
                       &As[(size_t)(i * 256 + wid * 64) * 8]);
            load_lds16(&B[(size_t)(col0 + r) * DM + k0 + c8],
                       &Bs[(size_t)(i * 256 + wid * 64) * 8]);
        }
        __syncthreads();
        #pragma unroll
        for (int ks = 0; ks < 2; ++ks) {
            const int kb = ks * 32 + (lane >> 4) * 8;
            bf16x8 af[4], bfr[4];
            #pragma unroll
            for (int m = 0; m < 4; ++m)
                af[m] = *(const bf16x8*)&As[(wr * 64 + m * 16 + (lane & 15)) * 64 + kb];
            #pragma unroll
            for (int n = 0; n < 4; ++n)
                bfr[n] = *(const bf16x8*)&Bs[(wc * 64 + n * 16 + (lane & 15)) * 64 + kb];
            // swapped operands: D = B_frag . A_frag  ->  D[h][token]
            #pragma unroll
            for (int hf = 0; hf < 4; ++hf)
                #pragma unroll
                for (int tf = 0; tf < 4; ++tf)
                    acc[hf][tf] = __builtin_amdgcn_mfma_f32_16x16x32_bf16(
                        bfr[hf], af[tf], acc[hf][tf], 0, 0, 0);
        }
        __syncthreads();
    }

    // ---- epilogue: coalesced f32x4 C-write (nt) + LDS candidate aggregation
    uint* cnt = (uint*)As;             // [128]
    uint* buf = (uint*)As + 128;       // [128][CSLOT]  (8.7 KB, aliases As)
    if (tid < 128) cnt[tid] = 0;
    __syncthreads();

    f32x4 ba[4];
    #pragma unroll
    for (int hf = 0; hf < 4; ++hf)
        ba[hf] = *(const f32x4*)&b_act[col0 + wc * 64 + hf * 16 + (lane >> 4) * 4];

    #pragma unroll
    for (int hf = 0; hf < 4; ++hf) {
        const int h0 = col0 + wc * 64 + hf * 16 + (lane >> 4) * 4;
        #pragma unroll
        for (int tf = 0; tf < 4; ++tf) {
            const int ltok = wr * 64 + tf * 16 + (lane & 15);   // local token
            f32x4 o = acc[hf][tf] + ba[hf];
            __builtin_nontemporal_store(
                o, (f32x4*)&pre[(size_t)(row0 + ltok) * DH + h0]);
            #pragma unroll
            for (int c = 0; c < 4; ++c) {
                if (o[c] > CAND_T) {
                    uint pos = atomicAdd(&cnt[ltok], 1u);
                    if (pos < CSLOT)
                        buf[ltok * CSLOT + pos] =
                            ((uint)f2bf(o[c]) << 16) | (uint)(16383 - (h0 + c));
                }
            }
        }
    }
    __syncthreads();
    if (tid < 128) {
        uint c = cnt[tid];
        if (c > 0) {
            uint m = c < CSLOT ? c : CSLOT;
            uint base = (uint)atomicAdd(&ccnt[row0 + tid], (int)m);
            if (c > CSLOT || base + c > NCAND) flags[row0 + tid] = 1u;
            for (uint k = 0; k < m && base + k < NCAND; ++k)
                cand[(size_t)(row0 + tid) * NCAND + base + k] = buf[tid * CSLOT + k];
        }
    }
}

// ---------------------------------------------------------------------------
// Fused top-32 + decode (DZ narrowed 0.08 -> 0.06; logic unchanged).
// ---------------------------------------------------------------------------
__global__ __launch_bounds__(512) void topk_recon(
    const float* __restrict__ x, const float* __restrict__ b_pre,
    const float* __restrict__ W, const float* __restrict__ b_act,
    const uint* __restrict__ cand, const int* __restrict__ ccnt,
    const uint* __restrict__ flags, const float* __restrict__ pre,
    const ushort* __restrict__ wdecT,
    float* __restrict__ sparse, float* __restrict__ recon)
{
    const int row = blockIdx.x;
    const int tid = threadIdx.x;
    const int wid = tid >> 6, lane = tid & 63;

    // zero sparse row (4096 x 16B / 512 threads, nontemporal)
    f32x4 z4 = {0.f, 0.f, 0.f, 0.f};
    f32x4* srow = (f32x4*)(sparse + (size_t)row * DH);
    #pragma unroll
    for (int i = 0; i < 8; ++i)
        __builtin_nontemporal_store(z4, &srow[tid + i * 512]);

    __shared__ float xs[DM];
    for (int i = tid; i < DM; i += 512)
        xs[i] = x[(size_t)row * DM + i] - b_pre[i];

    __shared__ float sv[NCAND];
    __shared__ float sex[NCAND];
    __shared__ int   si[NCAND];
    __shared__ int   zlist[NCAND];
    __shared__ float svals[KTOP];
    __shared__ int   sinds[KTOP];
    __shared__ float sa32;
    __shared__ int   scin, zn, nl;

    int n = min(ccnt[row], NCAND);
    {
        uint pk = (tid < n) ? cand[(size_t)row * NCAND + tid] : 0u;
        sv[tid] = (tid < n) ? bf2f((ushort)(pk >> 16)) : -1e30f;
        si[tid] = (tid < n) ? (int)(16383u - (pk & 0x3FFFu)) : -1;
    }
    if (tid == 0) { scin = 0; zn = 0; sa32 = -1e30f; }
    if (tid < KTOP) { svals[tid] = 0.f; sinds[tid] = -1; }
    __syncthreads();

    // fallback (expected ~never): overflow or degenerate
    const bool fb = (flags[row] != 0u) || n < 64;
    if (fb) {
        sv[tid] = -1e30f; si[tid] = -1;
        if (tid == 0) nl = 0;
        __syncthreads();
        const float* __restrict__ p = pre + (size_t)row * DH;
        float v[32];
        #pragma unroll
        for (int j = 0; j < 32; ++j) v[j] = p[j * 512 + tid];

        __shared__ int scount;
        float lo = -30.f, hi = 30.f, t = 0.f;
        for (int it = 0; it < 20; ++it) {
            t = 0.5f * (lo + hi);
            int c = 0;
            #pragma unroll
            for (int j = 0; j < 32; ++j) c += (v[j] > t);
            #pragma unroll
            for (int off = 32; off; off >>= 1) c += __shfl_down(c, off);
            if (tid == 0) scount = 0;
            __syncthreads();
            if ((tid & 63) == 0) atomicAdd(&scount, c);
            __syncthreads();
            int total = scount;
            __syncthreads();
            if (total >= 96 && total <= 450) break;
            if (total < 96) hi = t; else lo = t;
        }
        #pragma unroll
        for (int j = 0; j < 32; ++j) {
            if (v[j] > t) {
                int p2 = atomicAdd(&nl, 1);
                if (p2 < NCAND) { sv[p2] = v[j]; si[p2] = j * 512 + tid; }
            }
        }
        __syncthreads();
        n = min(nl, NCAND);
    }

    const float v  = sv[tid];
    const int   id = si[tid];
    sex[tid] = v;
    __syncthreads();

    // rank by count (val desc, idx asc), bounded to n (padded to 64)
    const int n_pad = (n + 63) & ~63;
    int rank = 0;
    for (int j = 0; j < n_pad; ++j) {
        float ov = sv[j];
        rank += (ov > v) || (ov == v && si[j] < id);
    }
    if (rank == 31) sa32 = v;
    __syncthreads();

    const float a32 = sa32;
    const bool cin  = v > a32 + DZ;
    const bool zone = !cin && (v >= a32 - DZ) && (id >= 0);

    unsigned long long bal = __ballot(cin);
    if (lane == 0) atomicAdd(&scin, (int)__popcll(bal));
    if (zone) { int p = atomicAdd(&zn, 1); zlist[p] = tid; }
    __syncthreads();

    const int cin_total = scin;
    const int znum = zn;

    // exact f32 recompute of zone members, one per wave (W rows L3-resident)
    for (int m = wid; m < znum; m += 8) {
        int t = zlist[m];
        int h = si[t];
        const float* wrow = W + (size_t)h * DM;
        float s = 0.f;
        #pragma unroll
        for (int c = 0; c < 16; ++c)
            s = fmaf(xs[lane + c * 64], wrow[lane + c * 64], s);
        #pragma unroll
        for (int off = 32; off; off >>= 1) s += __shfl_down(s, off);
        if (lane == 0) sex[t] = s + b_act[h];
    }
    __syncthreads();

    int slot = -1;
    float outv = 0.f;
    if (cin) { slot = rank; outv = v; }
    else if (zone) {
        float ev = sex[tid];
        int zrank = 0;
        for (int j = 0; j < znum; ++j) {
            int t2 = zlist[j];
            float ov = sex[t2];
            zrank += (ov > ev) || (ov == ev && si[t2] < id);
        }
        if (zrank < KTOP - cin_total) { slot = cin_total + zrank; outv = ev; }
    }
    if (slot >= 0 && slot < KTOP) {
        float r = fmaxf(outv, 0.f);
        svals[slot] = r;
        sinds[slot] = id;
        sparse[(size_t)row * DH + id] = r;
    }
    __syncthreads();

    // ---- fused decode: recon[row][d] = sum_j svals[j]*wdecT[sinds[j]][d]+b_pre[d]
    const int d0 = tid * 2;
    f32x2 a;
    a.x = b_pre[d0]; a.y = b_pre[d0 + 1];
    #pragma unroll 8
    for (int j = 0; j < KTOP; ++j) {
        float vj = svals[j];
        int h = sinds[j];
        if (vj != 0.f && h >= 0) {
            ushort2 w = *(const ushort2*)&wdecT[(size_t)h * DM + d0];
            a.x = fmaf(vj, bf2f(w.x), a.x);
            a.y = fmaf(vj, bf2f(w.y), a.y);
        }
    }
    __builtin_nontemporal_store(a, (f32x2*)&recon[(size_t)row * DM + d0]);
}

// ---------------------------------------------------------------------------
// Transpose W_dec [DM, DH] f32 -> W_dec^T [DH, DM] bf16
// ---------------------------------------------------------------------------
__global__ __launch_bounds__(256) void transpose_dec(
    const float* __restrict__ W, ushort* __restrict__ WT)
{
    __shared__ float t[32][33];
    const int tx = threadIdx.x;
    const int ty = threadIdx.y;
    const int h0 = blockIdx.x * 32;
    const int d0 = blockIdx.y * 32;
    #pragma unroll
    for (int r = 0; r < 4; ++r)
        t[ty + r * 8][tx] = W[(size_t)(d0 + ty + r * 8) * DH + h0 + tx];
    __syncthreads();
    #pragma unroll
    for (int r = 0; r < 4; ++r)
        WT[(size_t)(h0 + ty + r * 8) * DM + d0 + tx] = f2bf(t[tx][ty + r * 8]);
}

// ---------------------------------------------------------------------------
extern "C" void kernel_launch(void* const* d_in, const int* in_sizes, int n_in,
                              void* d_out, int out_size, void* d_ws, size_t ws_size,
                              hipStream_t stream)
{
    const float* x     = (const float*)d_in[0];
    const float* W_enc = (const float*)d_in[1];
    const float* W_dec = (const float*)d_in[2];
    const float* b_pre = (const float*)d_in[3];
    const float* b_act = (const float*)d_in[4];

    float* recon  = (float*)d_out;                       // [N, DM]
    float* sparse = recon + (size_t)N_TOK * DM;          // [N, DH]
    float* pre    = sparse + (size_t)N_TOK * DH;         // [N, DH]

    // bf16 staging of A/B inside the sparse output region (zeroed later by
    // topk_recon, which runs after gemm has consumed them)
    ushort* Abf = (ushort*)sparse;                       // 16.8 MB
    ushort* Bbf = Abf + (size_t)N_TOK * DM;              // 33.5 MB

    // workspace (~50.4 MB, under proven 52.4 MB footprint)
    int*    ccnt  = (int*)d_ws;                                   // 32 KB
    uint*   flags = (uint*)(ccnt + N_TOK);                        // 32 KB
    uint*   cand  = (uint*)(flags + N_TOK);                       // 16.78 MB
    ushort* wdecT = (ushort*)(cand + (size_t)N_TOK * NCAND);      // 33.5 MB

    // zero counters + flags only (64 KB; stale cand beyond count never read)
    (void)hipMemsetAsync(ccnt, 0, 2 * N_TOK * sizeof(int), stream);

    conv_fused<<<(NA + DH * DM) / 1024, 256, 0, stream>>>(x, b_pre, W_enc, Abf, Bbf);

    gemm_bf16<<<(N_TOK / 128) * (DH / 128), 256, 0, stream>>>(
        Abf, Bbf, b_act, pre, cand, ccnt, flags);

    transpose_dec<<<dim3(DH / 32, DM / 32), dim3(32, 8), 0, stream>>>(W_dec, wdecT);

    topk_recon<<<N_TOK, 512, 0, stream>>>(x, b_pre, W_enc, b_act,
                                          cand, ccnt, flags, pre, wdecT,
                                          sparse, recon);
}